// Round 5
// baseline (6818.587 us; speedup 1.0000x reference)
//
#include <hip/hip_runtime.h>
#include <hip/hip_bf16.h>

typedef short bf16x8 __attribute__((ext_vector_type(8)));
typedef float f32x4 __attribute__((ext_vector_type(4)));
typedef float f32x16 __attribute__((ext_vector_type(16)));
typedef unsigned int u32x4 __attribute__((ext_vector_type(4)));

typedef __attribute__((address_space(1))) void gvoid;
typedef __attribute__((address_space(3))) void lvoid;

__device__ __forceinline__ short f2b(float f) {
  __hip_bfloat16 h = __float2bfloat16(f);
  return __builtin_bit_cast(short, h);
}

__device__ __forceinline__ f32x4 mfma16(bf16x8 a, bf16x8 b, f32x4 c) {
  return __builtin_amdgcn_mfma_f32_16x16x32_bf16(a, b, c, 0, 0, 0);
}

__device__ __forceinline__ f32x16 mfma32(bf16x8 a, bf16x8 b, f32x16 c) {
  return __builtin_amdgcn_mfma_f32_32x32x16_bf16(a, b, c, 0, 0, 0);
}

__device__ __forceinline__ unsigned cvtpk(float lo, float hi) {
  unsigned r;
  asm("v_cvt_pk_bf16_f32 %0, %1, %2" : "=v"(r) : "v"(lo), "v"(hi));
  return r;
}

__device__ __forceinline__ void gload16(const void* g, void* l) {
  __builtin_amdgcn_global_load_lds((const gvoid*)g, (lvoid*)l, 16, 0, 0);
}

// ---------------------------------------------------------------- weights
__global__ __launch_bounds__(256) void convT_k(const float* __restrict__ src,
                                               short* __restrict__ dst, int K,
                                               int N, int scale_cols,
                                               float scale) {
  int idx = blockIdx.x * 256 + threadIdx.x;
  if (idx >= N * K) return;
  int n = idx / K, k = idx % K;
  float v = src[(size_t)k * N + n];
  if (n < scale_cols) v *= scale;
  dst[idx] = f2b(v);
}

__global__ __launch_bounds__(256) void scale_bias_k(const float* __restrict__ src,
                                                    float* __restrict__ dst,
                                                    int n, int scale_cols,
                                                    float scale) {
  int i = blockIdx.x * 256 + threadIdx.x;
  if (i >= n) return;
  dst[i] = src[i] * (i < scale_cols ? scale : 1.f);
}

// Combined rel-pos bias + shift mask table: tbl[cls][h][key][query], f32.
__global__ __launch_bounds__(256) void biasmask_k(const float* __restrict__ rpb,
                                                  float* __restrict__ tbl) {
  int idx = blockIdx.x * 256 + threadIdx.x;  // < 4*12*64*64
  int q = idx & 63, key = (idx >> 6) & 63;
  int hc = idx >> 12;  // cls*12 + h
  int h = hc % 12, cls = hc / 12;
  float v;
  if (q >= 49 || key >= 49) {
    v = -1e4f;
  } else {
    int i1 = q / 7, j1 = q % 7, i2 = key / 7, j2 = key % 7;
    v = rpb[(size_t)((i1 - i2 + 6) * 13 + (j1 - j2 + 6)) * 12 + h];
    int clsh = cls >> 1, clsw = cls & 1;
    int rq = (clsh ? 1 + (i1 >= 4) : 0) * 3 + (clsw ? 1 + (j1 >= 4) : 0);
    int rk = (clsh ? 1 + (i2 >= 4) : 0) * 3 + (clsw ? 1 + (j2 >= 4) : 0);
    if (rq != rk) v -= 100.f;
  }
  tbl[idx] = v;
}

// ---------------------------------------------------------------- layernorm
template <bool GATHER>
__device__ __forceinline__ void ln_body(const float* __restrict__ x,
                                        const float* __restrict__ gw,
                                        const float* __restrict__ bw,
                                        short* __restrict__ out) {
  const int lane = threadIdx.x & 63;
  const int t = (blockIdx.x << 2) + (threadIdx.x >> 6);
  size_t srow;
  if (GATHER) {
    int bb = t / 12544, rm2 = t % 12544;
    int wi = rm2 / 49, nn = rm2 % 49;
    int wh = wi >> 4, ww = wi & 15;
    int ii = nn / 7, jj = nn % 7;
    int rr = wh * 7 + ii + 3; if (rr >= 112) rr -= 112;
    int cc = ww * 7 + jj + 3; if (cc >= 112) cc -= 112;
    srow = ((size_t)bb * 12544 + rr * 112 + cc) * 384;
  } else {
    srow = (size_t)t * 384;
  }
  const float2* src = (const float2*)(x + srow);
  const float2* g2 = (const float2*)gw;
  const float2* b2 = (const float2*)bw;
  float2 u[3];
  float s = 0.f, ss = 0.f;
#pragma unroll
  for (int k = 0; k < 3; ++k) {
    u[k] = src[lane + (k << 6)];
    s += u[k].x + u[k].y;
    ss += u[k].x * u[k].x + u[k].y * u[k].y;
  }
#pragma unroll
  for (int m = 1; m < 64; m <<= 1) {
    s += __shfl_xor(s, m, 64);
    ss += __shfl_xor(ss, m, 64);
  }
  const float mean = s * (1.f / 384.f);
  const float var = ss * (1.f / 384.f) - mean * mean;
  const float rstd = rsqrtf(var + 1e-5f);
  unsigned* o = (unsigned*)(out + (size_t)t * 384);
#pragma unroll
  for (int k = 0; k < 3; ++k) {
    int c = lane + (k << 6);
    float2 gv = g2[c], bv = b2[c];
    unsigned lo = (unsigned short)f2b((u[k].x - mean) * rstd * gv.x + bv.x);
    unsigned hi = (unsigned short)f2b((u[k].y - mean) * rstd * gv.y + bv.y);
    o[c] = lo | (hi << 16);
  }
}

__global__ __launch_bounds__(256) void ln1_k(const float* __restrict__ x,
                                             const float* __restrict__ gw,
                                             const float* __restrict__ bw,
                                             short* __restrict__ out) {
  ln_body<true>(x, gw, bw, out);
}
__global__ __launch_bounds__(256) void ln2_k(const float* __restrict__ x,
                                             const float* __restrict__ gw,
                                             const float* __restrict__ bw,
                                             short* __restrict__ out) {
  ln_body<false>(x, gw, bw, out);
}

// ---------------------------------------------------------------- GEMM
// 128x128 tile, BK=32, 4 waves (2x2). Ring-3 STATIC LDS buffers with
// counted vmcnt (T3+T4): stage t+2 issued before COMPUTE(t); only one
// stage (4 vmem ops) crosses each barrier -> vmcnt(4), never a full
// drain in steady state. Static buffer names (round-2 lesson: runtime
// indexing forces conservative vmcnt(0) serialization). T5 setprio
// around the MFMA cluster.
template <int EPI>
__device__ __forceinline__ void gemm_body(
    const short* __restrict__ A, int lda, const short* __restrict__ BT,
    int ldb, const float* __restrict__ bias, int K, short* __restrict__ outh,
    int ldo, float* __restrict__ outf, const float* __restrict__ resid) {
  __shared__ __align__(16) short A0[4096], B0[4096];
  __shared__ __align__(16) short A1[4096], B1[4096];
  __shared__ __align__(16) short A2[4096], B2[4096];
  const int tid = threadIdx.x;
  const int gx = gridDim.x;
  int lin = blockIdx.y * gx + blockIdx.x;
  const int cpx = (gx * gridDim.y) >> 3;
  lin = (lin & 7) * cpx + (lin >> 3);
  const int m0 = (lin / gx) << 7, n0 = (lin % gx) << 7;
  const int lane = tid & 63;
  const int wave = tid >> 6;
  const int wr = (wave >> 1) << 6, wc = (wave & 1) << 6;
  const int g = lane >> 4, q = lane & 15;
  const int loff = tid << 3;

  f32x4 acc[4][4];
#pragma unroll
  for (int i = 0; i < 4; ++i)
#pragma unroll
    for (int j = 0; j < 4; ++j) acc[i][j] = (f32x4){0.f, 0.f, 0.f, 0.f};

  const short* Ab = A + (size_t)(m0 + (tid >> 2)) * lda + ((tid & 3) << 3);
  const short* Ab2 = Ab + (size_t)64 * lda;
  const short* Bb = BT + (size_t)(n0 + (tid >> 2)) * ldb + ((tid & 3) << 3);
  const short* Bb2 = Bb + (size_t)64 * ldb;

#define STAGE(kt, dA, dB)                   \
  do {                                      \
    gload16(Ab + (kt), &dA[loff]);          \
    gload16(Ab2 + (kt), &dA[loff + 2048]);  \
    gload16(Bb + (kt), &dB[loff]);          \
    gload16(Bb2 + (kt), &dB[loff + 2048]);  \
  } while (0)

#define COMPUTE(SA, SB)                                               \
  do {                                                                \
    bf16x8 af[4], bfv[4];                                             \
    _Pragma("unroll") for (int mi = 0; mi < 4; ++mi)                  \
        af[mi] = *(const bf16x8*)&SA[(wr + mi * 16 + q) * 32 + g * 8];\
    _Pragma("unroll") for (int ni = 0; ni < 4; ++ni)                  \
        bfv[ni] = *(const bf16x8*)&SB[(wc + ni * 16 + q) * 32 + g * 8];\
    __builtin_amdgcn_s_setprio(1);                                    \
    _Pragma("unroll") for (int mi = 0; mi < 4; ++mi)                  \
        _Pragma("unroll") for (int ni = 0; ni < 4; ++ni)              \
            acc[mi][ni] = mfma16(af[mi], bfv[ni], acc[mi][ni]);       \
    __builtin_amdgcn_s_setprio(0);                                    \
  } while (0)

#define VM4 asm volatile("s_waitcnt vmcnt(4)" ::: "memory")
#define VM0 asm volatile("s_waitcnt vmcnt(0)" ::: "memory")
#define BAR __builtin_amdgcn_s_barrier()

  const int nt = K >> 5;  // 12 or 24 here (multiples of 3, >= 6)
  STAGE(0, A0, B0);
  STAGE(32, A1, B1);
  VM4;  // tile 0 landed (oldest 4 of 8)
  BAR;
  for (int t = 0; t < nt; t += 3) {
    // sub 0: compute b0, stage t+2 -> b2
    if (t + 2 < nt) STAGE((t + 2) << 5, A2, B2);
    COMPUTE(A0, B0);
    if (t + 2 < nt) VM4; else VM0;  // ensure stage(t+1) landed
    BAR;
    if (t + 1 >= nt) break;
    // sub 1: compute b1, stage t+3 -> b0
    if (t + 3 < nt) STAGE((t + 3) << 5, A0, B0);
    COMPUTE(A1, B1);
    if (t + 3 < nt) VM4; else VM0;  // ensure stage(t+2) landed
    BAR;
    if (t + 2 >= nt) break;
    // sub 2: compute b2, stage t+4 -> b1
    if (t + 4 < nt) STAGE((t + 4) << 5, A1, B1);
    COMPUTE(A2, B2);
    if (t + 4 < nt) VM4; else VM0;  // ensure stage(t+3) landed
    BAR;
  }
#undef STAGE
#undef COMPUTE
#undef VM4
#undef VM0
#undef BAR

  float bv[4];
#pragma unroll
  for (int ni = 0; ni < 4; ++ni)
    bv[ni] = bias ? bias[n0 + wc + ni * 16 + q] : 0.f;

#pragma unroll
  for (int mi = 0; mi < 4; ++mi) {
#pragma unroll
    for (int r = 0; r < 4; ++r) {
      const int grow = m0 + wr + mi * 16 + g * 4 + r;
      size_t orow;
      if constexpr (EPI == 2) {
        int bb = grow / 12544, rm2 = grow % 12544;
        int wi = rm2 / 49, nn = rm2 % 49;
        int wh = wi >> 4, ww = wi & 15;
        int ii = nn / 7, jj = nn % 7;
        int rr = wh * 7 + ii + 3; if (rr >= 112) rr -= 112;
        int cc = ww * 7 + jj + 3; if (cc >= 112) cc -= 112;
        orow = ((size_t)bb * 12544 + rr * 112 + cc) * 384;
      } else {
        orow = (size_t)grow * (size_t)ldo;
      }
#pragma unroll
      for (int ni = 0; ni < 4; ++ni) {
        const int gcol = n0 + wc + ni * 16 + q;
        float v = acc[mi][ni][r] + bv[ni];
        if constexpr (EPI == 0) {
          outh[orow + gcol] = f2b(v);
        } else if constexpr (EPI == 1) {
          v = 0.5f * v * (1.f + erff(v * 0.70710678118f));
          outh[orow + gcol] = f2b(v);
        } else if constexpr (EPI == 2) {
          outf[orow + gcol] = resid[orow + gcol] + v;
        } else {
          outf[orow + gcol] += v;
        }
      }
    }
  }
}

#define GEMM_WRAP(NAME, EPI)                                                   \
  __global__ __launch_bounds__(256, 3) void NAME(                              \
      const short* __restrict__ A, int lda, const short* __restrict__ BT,      \
      int ldb, const float* __restrict__ bias, int K,                          \
      short* __restrict__ outh, int ldo, float* __restrict__ outf,             \
      const float* __restrict__ resid) {                                       \
    gemm_body<EPI>(A, lda, BT, ldb, bias, K, outh, ldo, outf, resid);          \
  }
GEMM_WRAP(gemm_qkv_k, 0)
GEMM_WRAP(gemm_fc1_k, 1)
GEMM_WRAP(gemm_proj_k, 2)
GEMM_WRAP(gemm_fc2_k, 3)

// ---------------------------------------------------------------- attention
// One wave per (window, head), 4 waves/block, ZERO LDS. Swapped QK^T via
// mfma_32x32x16; in-register softmax; cvt_pk + shfl_xor(32) assembles PV
// A-frags (T12); V^T B-frags straight from global; bias+mask from table.
__global__ __launch_bounds__(256) void attn_k(const short* __restrict__ qkv,
                                              const float* __restrict__ tbl,
                                              short* __restrict__ out) {
  const int lane = threadIdx.x & 63;
  const int task = blockIdx.x * 4 + (threadIdx.x >> 6);
  const int win = task / 12;
  const int h = task - win * 12;
  const int wh = (win >> 4) & 15, ww = win & 15;
  const int cls = ((wh == 15) ? 2 : 0) + ((ww == 15) ? 1 : 0);
  const int l31 = lane & 31, h5 = lane >> 5;
  const size_t tokbase = (size_t)win * 49;
  const short* base = qkv + tokbase * 1152 + h * 32;
  const bf16x8 zero8 = {0, 0, 0, 0, 0, 0, 0, 0};

  bf16x8 kf[2][2];
#pragma unroll
  for (int mi = 0; mi < 2; ++mi) {
    int row = l31 + 32 * mi;
#pragma unroll
    for (int s = 0; s < 2; ++s)
      kf[mi][s] = (row < 49)
                      ? *(const bf16x8*)(base + (size_t)row * 1152 + 384 +
                                         16 * s + 8 * h5)
                      : zero8;
  }
  bf16x8 vf[4];
#pragma unroll
  for (int kt = 0; kt < 4; ++kt) {
#pragma unroll
    for (int e = 0; e < 8; ++e) {
      int key = 16 * kt + 8 * h5 + e;
      vf[kt][e] = (key < 49) ? base[(size_t)key * 1152 + 768 + l31] : (short)0;
    }
  }

  const float* tb = tbl + ((size_t)(cls * 12 + h) << 12);

#pragma unroll
  for (int ni = 0; ni < 2; ++ni) {
    bf16x8 qf[2];
    int qrow = l31 + 32 * ni;
#pragma unroll
    for (int s = 0; s < 2; ++s)
      qf[s] = (qrow < 49)
                  ? *(const bf16x8*)(base + (size_t)qrow * 1152 + 16 * s +
                                     8 * h5)
                  : zero8;
    f32x16 st[2];
#pragma unroll
    for (int mi = 0; mi < 2; ++mi) {
      st[mi] = mfma32(kf[mi][0], qf[0], (f32x16)(0.f));
      st[mi] = mfma32(kf[mi][1], qf[1], st[mi]);
    }
#pragma unroll
    for (int mi = 0; mi < 2; ++mi)
#pragma unroll
      for (int r = 0; r < 16; ++r) {
        int koff = (r & 3) + 8 * (r >> 2) + 4 * h5;
        st[mi][r] += tb[(size_t)(32 * mi + koff) * 64 + 32 * ni + l31];
      }
    float mx = st[0][0];
#pragma unroll
    for (int r = 1; r < 16; ++r) mx = fmaxf(mx, st[0][r]);
#pragma unroll
    for (int r = 0; r < 16; ++r) mx = fmaxf(mx, st[1][r]);
    mx = fmaxf(mx, __shfl_xor(mx, 32, 64));
    float sm = 0.f;
#pragma unroll
    for (int mi = 0; mi < 2; ++mi)
#pragma unroll
      for (int r = 0; r < 16; ++r) {
        float e = __expf(st[mi][r] - mx);
        st[mi][r] = e;
        sm += e;
      }
    sm += __shfl_xor(sm, 32, 64);
    const float rinv = 1.f / sm;
#pragma unroll
    for (int mi = 0; mi < 2; ++mi)
#pragma unroll
      for (int r = 0; r < 16; ++r) st[mi][r] *= rinv;

    f32x16 acc = (f32x16)(0.f);
#pragma unroll
    for (int kt = 0; kt < 4; ++kt) {
      const int mi = kt >> 1, b8 = (kt & 1) * 8;
      unsigned q0l = cvtpk(st[mi][b8 + 0], st[mi][b8 + 1]);
      unsigned q0h = cvtpk(st[mi][b8 + 2], st[mi][b8 + 3]);
      unsigned q1l = cvtpk(st[mi][b8 + 4], st[mi][b8 + 5]);
      unsigned q1h = cvtpk(st[mi][b8 + 6], st[mi][b8 + 7]);
      unsigned sl = h5 ? q0l : q1l, sh = h5 ? q0h : q1h;
      unsigned kl = h5 ? q1l : q0l, kh = h5 ? q1h : q0h;
      unsigned rl = (unsigned)__shfl_xor((int)sl, 32, 64);
      unsigned rh = (unsigned)__shfl_xor((int)sh, 32, 64);
      u32x4 fr;
      fr[0] = h5 ? rl : kl;
      fr[1] = h5 ? rh : kh;
      fr[2] = h5 ? kl : rl;
      fr[3] = h5 ? kh : rh;
      acc = mfma32(__builtin_bit_cast(bf16x8, fr), vf[kt], acc);
    }
#pragma unroll
    for (int r = 0; r < 16; ++r) {
      int query = 32 * ni + (r & 3) + 8 * (r >> 2) + 4 * h5;
      if (ni == 0 || query < 49)
        out[(tokbase + query) * 384 + h * 32 + l31] = f2b(acc[r]);
    }
  }
}

// ---------------------------------------------------------------- launch
extern "C" void kernel_launch(void* const* d_in, const int* in_sizes, int n_in,
                              void* d_out, int out_size, void* d_ws,
                              size_t ws_size, hipStream_t stream) {
  const float* x = (const float*)d_in[0];
  const float* n1g = (const float*)d_in[1];
  const float* n1b = (const float*)d_in[2];
  const float* qkvw = (const float*)d_in[3];
  const float* qkvb = (const float*)d_in[4];
  const float* projw = (const float*)d_in[5];
  const float* projb = (const float*)d_in[6];
  const float* rpb = (const float*)d_in[7];
  const float* n2g = (const float*)d_in[8];
  const float* n2b = (const float*)d_in[9];
  const float* fc1w = (const float*)d_in[10];
  const float* fc1b = (const float*)d_in[11];
  const float* fc2w = (const float*)d_in[12];
  const float* fc2b = (const float*)d_in[13];
  float* out = (float*)d_out;

  char* ws = (char*)d_ws;
  short* w_qkvT = (short*)(ws + 0);            // 884736 B
  short* w_projT = (short*)(ws + 884736);      // 294912 B
  short* w_fc1T = (short*)(ws + 1179648);      // 1179648 B
  short* w_fc2T = (short*)(ws + 2359296);      // 1179648 B
  float* w_qb = (float*)(ws + 3538944);        // 4608 B
  float* tbl = (float*)(ws + 3543552);         // 786432 B
  const size_t o_qkv = 4329984;
  short* qkvbuf = (short*)(ws + o_qkv);        // 462422016 B
  const size_t o_hwin = o_qkv + 462422016ull;
  short* hwin = (short*)(ws + o_hwin);         // 154140672 B
  const size_t o_fc1 = o_hwin + 154140672ull;

  int NC;
  size_t fc1_off = o_fc1;
  if (ws_size >= o_fc1 + 616562688ull) NC = 1;
  else if (ws_size >= o_fc1 + 308281344ull) NC = 2;
  else if (ws_size >= o_fc1 + 154140672ull) NC = 4;
  else { NC = 4; fc1_off = o_hwin; }
  short* fc1c = (short*)(ws + fc1_off);
  short* h2 = qkvbuf;

  const float qscale = 0.17677669529663687f;

  convT_k<<<(442368 + 255) / 256, 256, 0, stream>>>(qkvw, w_qkvT, 384, 1152, 384, qscale);
  convT_k<<<(147456 + 255) / 256, 256, 0, stream>>>(projw, w_projT, 384, 384, 0, 1.f);
  convT_k<<<(589824 + 255) / 256, 256, 0, stream>>>(fc1w, w_fc1T, 384, 1536, 0, 1.f);
  convT_k<<<(589824 + 255) / 256, 256, 0, stream>>>(fc2w, w_fc2T, 1536, 384, 0, 1.f);
  scale_bias_k<<<5, 256, 0, stream>>>(qkvb, w_qb, 1152, 384, qscale);
  biasmask_k<<<768, 256, 0, stream>>>(rpb, tbl);

  ln1_k<<<50176, 256, 0, stream>>>(x, n1g, n1b, hwin);
  gemm_qkv_k<<<dim3(9, 1568), 256, 0, stream>>>(hwin, 384, w_qkvT, 384, w_qb,
                                                384, qkvbuf, 1152, nullptr,
                                                nullptr);
  attn_k<<<12288, 256, 0, stream>>>(qkvbuf, tbl, hwin);
  gemm_proj_k<<<dim3(3, 1568), 256, 0, stream>>>(hwin, 384, w_projT, 384,
                                                 projb, 384, nullptr, 384, out,
                                                 x);
  ln2_k<<<50176, 256, 0, stream>>>(out, n2g, n2b, h2);
  const int CK = 1536 / NC;
  for (int c = 0; c < NC; ++c) {
    gemm_fc1_k<<<dim3(CK >> 7, 1568), 256, 0, stream>>>(
        h2, 384, w_fc1T + (size_t)c * CK * 384, 384, fc1b + c * CK, 384, fc1c,
        CK, nullptr, nullptr);
    gemm_fc2_k<<<dim3(3, 1568), 256, 0, stream>>>(
        fc1c, CK, w_fc2T + c * CK, 1536, (c == 0) ? fc2b : nullptr, CK,
        nullptr, 384, out, nullptr);
  }
}

// Round 6
// 2176.446 us; speedup vs baseline: 3.1329x; 3.1329x over previous
//
#include <hip/hip_runtime.h>
#include <hip/hip_bf16.h>

typedef short bf16x8 __attribute__((ext_vector_type(8)));
typedef float f32x4 __attribute__((ext_vector_type(4)));
typedef float f32x16 __attribute__((ext_vector_type(16)));
typedef unsigned int u32x4 __attribute__((ext_vector_type(4)));

typedef __attribute__((address_space(1))) void gvoid;
typedef __attribute__((address_space(3))) void lvoid;

__device__ __forceinline__ short f2b(float f) {
  __hip_bfloat16 h = __float2bfloat16(f);
  return __builtin_bit_cast(short, h);
}

__device__ __forceinline__ f32x4 mfma16(bf16x8 a, bf16x8 b, f32x4 c) {
  return __builtin_amdgcn_mfma_f32_16x16x32_bf16(a, b, c, 0, 0, 0);
}

__device__ __forceinline__ f32x16 mfma32(bf16x8 a, bf16x8 b, f32x16 c) {
  return __builtin_amdgcn_mfma_f32_32x32x16_bf16(a, b, c, 0, 0, 0);
}

__device__ __forceinline__ unsigned cvtpk(float lo, float hi) {
  unsigned r;
  asm("v_cvt_pk_bf16_f32 %0, %1, %2" : "=v"(r) : "v"(lo), "v"(hi));
  return r;
}

__device__ __forceinline__ void gload16(const void* g, void* l) {
  __builtin_amdgcn_global_load_lds((const gvoid*)g, (lvoid*)l, 16, 0, 0);
}

// ---------------------------------------------------------------- weights
__global__ __launch_bounds__(256) void convT_k(const float* __restrict__ src,
                                               short* __restrict__ dst, int K,
                                               int N, int scale_cols,
                                               float scale) {
  int idx = blockIdx.x * 256 + threadIdx.x;
  if (idx >= N * K) return;
  int n = idx / K, k = idx % K;
  float v = src[(size_t)k * N + n];
  if (n < scale_cols) v *= scale;
  dst[idx] = f2b(v);
}

__global__ __launch_bounds__(256) void scale_bias_k(const float* __restrict__ src,
                                                    float* __restrict__ dst,
                                                    int n, int scale_cols,
                                                    float scale) {
  int i = blockIdx.x * 256 + threadIdx.x;
  if (i >= n) return;
  dst[i] = src[i] * (i < scale_cols ? scale : 1.f);
}

// Combined rel-pos bias + shift mask table: tbl[cls][h][key][query], f32.
__global__ __launch_bounds__(256) void biasmask_k(const float* __restrict__ rpb,
                                                  float* __restrict__ tbl) {
  int idx = blockIdx.x * 256 + threadIdx.x;  // < 4*12*64*64
  int q = idx & 63, key = (idx >> 6) & 63;
  int hc = idx >> 12;  // cls*12 + h
  int h = hc % 12, cls = hc / 12;
  float v;
  if (q >= 49 || key >= 49) {
    v = -1e4f;
  } else {
    int i1 = q / 7, j1 = q % 7, i2 = key / 7, j2 = key % 7;
    v = rpb[(size_t)((i1 - i2 + 6) * 13 + (j1 - j2 + 6)) * 12 + h];
    int clsh = cls >> 1, clsw = cls & 1;
    int rq = (clsh ? 1 + (i1 >= 4) : 0) * 3 + (clsw ? 1 + (j1 >= 4) : 0);
    int rk = (clsh ? 1 + (i2 >= 4) : 0) * 3 + (clsw ? 1 + (j2 >= 4) : 0);
    if (rq != rk) v -= 100.f;
  }
  tbl[idx] = v;
}

// ---------------------------------------------------------------- layernorm
template <bool GATHER>
__device__ __forceinline__ void ln_body(const float* __restrict__ x,
                                        const float* __restrict__ gw,
                                        const float* __restrict__ bw,
                                        short* __restrict__ out) {
  const int lane = threadIdx.x & 63;
  const int t = (blockIdx.x << 2) + (threadIdx.x >> 6);
  size_t srow;
  if (GATHER) {
    int bb = t / 12544, rm2 = t % 12544;
    int wi = rm2 / 49, nn = rm2 % 49;
    int wh = wi >> 4, ww = wi & 15;
    int ii = nn / 7, jj = nn % 7;
    int rr = wh * 7 + ii + 3; if (rr >= 112) rr -= 112;
    int cc = ww * 7 + jj + 3; if (cc >= 112) cc -= 112;
    srow = ((size_t)bb * 12544 + rr * 112 + cc) * 384;
  } else {
    srow = (size_t)t * 384;
  }
  const float2* src = (const float2*)(x + srow);
  const float2* g2 = (const float2*)gw;
  const float2* b2 = (const float2*)bw;
  float2 u[3];
  float s = 0.f, ss = 0.f;
#pragma unroll
  for (int k = 0; k < 3; ++k) {
    u[k] = src[lane + (k << 6)];
    s += u[k].x + u[k].y;
    ss += u[k].x * u[k].x + u[k].y * u[k].y;
  }
#pragma unroll
  for (int m = 1; m < 64; m <<= 1) {
    s += __shfl_xor(s, m, 64);
    ss += __shfl_xor(ss, m, 64);
  }
  const float mean = s * (1.f / 384.f);
  const float var = ss * (1.f / 384.f) - mean * mean;
  const float rstd = rsqrtf(var + 1e-5f);
  unsigned* o = (unsigned*)(out + (size_t)t * 384);
#pragma unroll
  for (int k = 0; k < 3; ++k) {
    int c = lane + (k << 6);
    float2 gv = g2[c], bv = b2[c];
    unsigned lo = (unsigned short)f2b((u[k].x - mean) * rstd * gv.x + bv.x);
    unsigned hi = (unsigned short)f2b((u[k].y - mean) * rstd * gv.y + bv.y);
    o[c] = lo | (hi << 16);
  }
}

__global__ __launch_bounds__(256) void ln1_k(const float* __restrict__ x,
                                             const float* __restrict__ gw,
                                             const float* __restrict__ bw,
                                             short* __restrict__ out) {
  ln_body<true>(x, gw, bw, out);
}
__global__ __launch_bounds__(256) void ln2_k(const float* __restrict__ x,
                                             const float* __restrict__ gw,
                                             const float* __restrict__ bw,
                                             short* __restrict__ out) {
  ln_body<false>(x, gw, bw, out);
}

// ---------------------------------------------------------------- GEMM
// 128x128 tile, BK=32, 4 waves (2x2). Ring-3 STATIC LDS buffers, raw
// s_barrier + counted vmcnt(4) (T3+T4): stage t+2 issued before
// COMPUTE(t); exactly one stage (4 vmem ops) crosses each barrier.
// Round-5 lesson: no launch_bounds min-waves (acc spilled to scratch ->
// 2.4GB/4GB HBM amplification), no setprio, branch-free main loop.
// Single barrier/phase is WAR-safe: MFMA's lgkmcnt forces ds_read
// completion before the end-of-phase barrier. Requires nt%3==0, nt>=6.
template <int EPI>
__device__ __forceinline__ void gemm_body(
    const short* __restrict__ A, int lda, const short* __restrict__ BT,
    int ldb, const float* __restrict__ bias, int K, short* __restrict__ outh,
    int ldo, float* __restrict__ outf, const float* __restrict__ resid) {
  __shared__ __align__(16) short A0[4096], B0[4096];
  __shared__ __align__(16) short A1[4096], B1[4096];
  __shared__ __align__(16) short A2[4096], B2[4096];
  const int tid = threadIdx.x;
  const int gx = gridDim.x;
  int lin = blockIdx.y * gx + blockIdx.x;
  const int cpx = (gx * gridDim.y) >> 3;
  lin = (lin & 7) * cpx + (lin >> 3);
  const int m0 = (lin / gx) << 7, n0 = (lin % gx) << 7;
  const int lane = tid & 63;
  const int wave = tid >> 6;
  const int wr = (wave >> 1) << 6, wc = (wave & 1) << 6;
  const int g = lane >> 4, q = lane & 15;
  const int loff = tid << 3;

  f32x4 acc[4][4];
#pragma unroll
  for (int i = 0; i < 4; ++i)
#pragma unroll
    for (int j = 0; j < 4; ++j) acc[i][j] = (f32x4){0.f, 0.f, 0.f, 0.f};

  const short* Ab = A + (size_t)(m0 + (tid >> 2)) * lda + ((tid & 3) << 3);
  const short* Ab2 = Ab + (size_t)64 * lda;
  const short* Bb = BT + (size_t)(n0 + (tid >> 2)) * ldb + ((tid & 3) << 3);
  const short* Bb2 = Bb + (size_t)64 * ldb;

#define STAGE(kt, dA, dB)                   \
  do {                                      \
    gload16(Ab + (kt), &dA[loff]);          \
    gload16(Ab2 + (kt), &dA[loff + 2048]);  \
    gload16(Bb + (kt), &dB[loff]);          \
    gload16(Bb2 + (kt), &dB[loff + 2048]);  \
  } while (0)

#define COMPUTE(SA, SB)                                               \
  do {                                                                \
    bf16x8 af[4], bfv[4];                                             \
    _Pragma("unroll") for (int mi = 0; mi < 4; ++mi)                  \
        af[mi] = *(const bf16x8*)&SA[(wr + mi * 16 + q) * 32 + g * 8];\
    _Pragma("unroll") for (int ni = 0; ni < 4; ++ni)                  \
        bfv[ni] = *(const bf16x8*)&SB[(wc + ni * 16 + q) * 32 + g * 8];\
    _Pragma("unroll") for (int mi = 0; mi < 4; ++mi)                  \
        _Pragma("unroll") for (int ni = 0; ni < 4; ++ni)              \
            acc[mi][ni] = mfma16(af[mi], bfv[ni], acc[mi][ni]);       \
  } while (0)

#define VM4                                           \
  do {                                                \
    asm volatile("s_waitcnt vmcnt(4)" ::: "memory");  \
    __builtin_amdgcn_sched_barrier(0);                \
  } while (0)
#define VM0                                           \
  do {                                                \
    asm volatile("s_waitcnt vmcnt(0)" ::: "memory");  \
    __builtin_amdgcn_sched_barrier(0);                \
  } while (0)
#define BAR __builtin_amdgcn_s_barrier()

  const int nt = K >> 5;  // 12, 24, or 48 here: %3==0, >=12
  STAGE(0, A0, B0);
  STAGE(32, A1, B1);
  VM4;  // tile 0 landed
  BAR;
  int kk = 64;
  for (int t = 0; t + 3 < nt; t += 3) {
    STAGE(kk, A2, B2);
    COMPUTE(A0, B0);
    VM4;  // tile t+1 landed (only stage(t+2) still outstanding)
    BAR;
    STAGE(kk + 32, A0, B0);
    COMPUTE(A1, B1);
    VM4;
    BAR;
    STAGE(kk + 64, A1, B1);
    COMPUTE(A2, B2);
    VM4;
    BAR;
    kk += 96;
  }
  // tail: tiles nt-3 (A0), nt-2 (A1, outstanding), nt-1 (stage now)
  STAGE(kk, A2, B2);
  COMPUTE(A0, B0);
  VM4;
  BAR;
  COMPUTE(A1, B1);
  VM0;
  BAR;
  COMPUTE(A2, B2);
#undef STAGE
#undef COMPUTE
#undef VM4
#undef VM0
#undef BAR

  float bv[4];
#pragma unroll
  for (int ni = 0; ni < 4; ++ni)
    bv[ni] = bias ? bias[n0 + wc + ni * 16 + q] : 0.f;

#pragma unroll
  for (int mi = 0; mi < 4; ++mi) {
#pragma unroll
    for (int r = 0; r < 4; ++r) {
      const int grow = m0 + wr + mi * 16 + g * 4 + r;
      size_t orow;
      if constexpr (EPI == 2) {
        int bb = grow / 12544, rm2 = grow % 12544;
        int wi = rm2 / 49, nn = rm2 % 49;
        int wh = wi >> 4, ww = wi & 15;
        int ii = nn / 7, jj = nn % 7;
        int rr = wh * 7 + ii + 3; if (rr >= 112) rr -= 112;
        int cc = ww * 7 + jj + 3; if (cc >= 112) cc -= 112;
        orow = ((size_t)bb * 12544 + rr * 112 + cc) * 384;
      } else {
        orow = (size_t)grow * (size_t)ldo;
      }
#pragma unroll
      for (int ni = 0; ni < 4; ++ni) {
        const int gcol = n0 + wc + ni * 16 + q;
        float v = acc[mi][ni][r] + bv[ni];
        if constexpr (EPI == 0) {
          outh[orow + gcol] = f2b(v);
        } else if constexpr (EPI == 1) {
          v = 0.5f * v * (1.f + erff(v * 0.70710678118f));
          outh[orow + gcol] = f2b(v);
        } else if constexpr (EPI == 2) {
          outf[orow + gcol] = resid[orow + gcol] + v;
        } else {
          outf[orow + gcol] += v;
        }
      }
    }
  }
}

#define GEMM_WRAP(NAME, EPI)                                                   \
  __global__ __launch_bounds__(256) void NAME(                                 \
      const short* __restrict__ A, int lda, const short* __restrict__ BT,      \
      int ldb, const float* __restrict__ bias, int K,                          \
      short* __restrict__ outh, int ldo, float* __restrict__ outf,             \
      const float* __restrict__ resid) {                                       \
    gemm_body<EPI>(A, lda, BT, ldb, bias, K, outh, ldo, outf, resid);          \
  }
GEMM_WRAP(gemm_qkv_k, 0)
GEMM_WRAP(gemm_fc1_k, 1)
GEMM_WRAP(gemm_proj_k, 2)
GEMM_WRAP(gemm_fc2_k, 3)

// ---------------------------------------------------------------- attention
// One wave per (window, head), 4 waves/block, ZERO LDS. Swapped QK^T via
// mfma_32x32x16; in-register softmax; cvt_pk + shfl_xor(32) assembles PV
// A-frags (T12); V^T B-frags straight from global; bias+mask from table.
__global__ __launch_bounds__(256) void attn_k(const short* __restrict__ qkv,
                                              const float* __restrict__ tbl,
                                              short* __restrict__ out) {
  const int lane = threadIdx.x & 63;
  const int task = blockIdx.x * 4 + (threadIdx.x >> 6);
  const int win = task / 12;
  const int h = task - win * 12;
  const int wh = (win >> 4) & 15, ww = win & 15;
  const int cls = ((wh == 15) ? 2 : 0) + ((ww == 15) ? 1 : 0);
  const int l31 = lane & 31, h5 = lane >> 5;
  const size_t tokbase = (size_t)win * 49;
  const short* base = qkv + tokbase * 1152 + h * 32;
  const bf16x8 zero8 = {0, 0, 0, 0, 0, 0, 0, 0};

  bf16x8 kf[2][2];
#pragma unroll
  for (int mi = 0; mi < 2; ++mi) {
    int row = l31 + 32 * mi;
#pragma unroll
    for (int s = 0; s < 2; ++s)
      kf[mi][s] = (row < 49)
                      ? *(const bf16x8*)(base + (size_t)row * 1152 + 384 +
                                         16 * s + 8 * h5)
                      : zero8;
  }
  bf16x8 vf[4];
#pragma unroll
  for (int kt = 0; kt < 4; ++kt) {
#pragma unroll
    for (int e = 0; e < 8; ++e) {
      int key = 16 * kt + 8 * h5 + e;
      vf[kt][e] = (key < 49) ? base[(size_t)key * 1152 + 768 + l31] : (short)0;
    }
  }

  const float* tb = tbl + ((size_t)(cls * 12 + h) << 12);

#pragma unroll
  for (int ni = 0; ni < 2; ++ni) {
    bf16x8 qf[2];
    int qrow = l31 + 32 * ni;
#pragma unroll
    for (int s = 0; s < 2; ++s)
      qf[s] = (qrow < 49)
                  ? *(const bf16x8*)(base + (size_t)qrow * 1152 + 16 * s +
                                     8 * h5)
                  : zero8;
    f32x16 st[2];
#pragma unroll
    for (int mi = 0; mi < 2; ++mi) {
      st[mi] = mfma32(kf[mi][0], qf[0], (f32x16)(0.f));
      st[mi] = mfma32(kf[mi][1], qf[1], st[mi]);
    }
#pragma unroll
    for (int mi = 0; mi < 2; ++mi)
#pragma unroll
      for (int r = 0; r < 16; ++r) {
        int koff = (r & 3) + 8 * (r >> 2) + 4 * h5;
        st[mi][r] += tb[(size_t)(32 * mi + koff) * 64 + 32 * ni + l31];
      }
    float mx = st[0][0];
#pragma unroll
    for (int r = 1; r < 16; ++r) mx = fmaxf(mx, st[0][r]);
#pragma unroll
    for (int r = 0; r < 16; ++r) mx = fmaxf(mx, st[1][r]);
    mx = fmaxf(mx, __shfl_xor(mx, 32, 64));
    float sm = 0.f;
#pragma unroll
    for (int mi = 0; mi < 2; ++mi)
#pragma unroll
      for (int r = 0; r < 16; ++r) {
        float e = __expf(st[mi][r] - mx);
        st[mi][r] = e;
        sm += e;
      }
    sm += __shfl_xor(sm, 32, 64);
    const float rinv = 1.f / sm;
#pragma unroll
    for (int mi = 0; mi < 2; ++mi)
#pragma unroll
      for (int r = 0; r < 16; ++r) st[mi][r] *= rinv;

    f32x16 acc = (f32x16)(0.f);
#pragma unroll
    for (int kt = 0; kt < 4; ++kt) {
      const int mi = kt >> 1, b8 = (kt & 1) * 8;
      unsigned q0l = cvtpk(st[mi][b8 + 0], st[mi][b8 + 1]);
      unsigned q0h = cvtpk(st[mi][b8 + 2], st[mi][b8 + 3]);
      unsigned q1l = cvtpk(st[mi][b8 + 4], st[mi][b8 + 5]);
      unsigned q1h = cvtpk(st[mi][b8 + 6], st[mi][b8 + 7]);
      unsigned sl = h5 ? q0l : q1l, sh = h5 ? q0h : q1h;
      unsigned kl = h5 ? q1l : q0l, kh = h5 ? q1h : q0h;
      unsigned rl = (unsigned)__shfl_xor((int)sl, 32, 64);
      unsigned rh = (unsigned)__shfl_xor((int)sh, 32, 64);
      u32x4 fr;
      fr[0] = h5 ? rl : kl;
      fr[1] = h5 ? rh : kh;
      fr[2] = h5 ? kl : rl;
      fr[3] = h5 ? kh : rh;
      acc = mfma32(__builtin_bit_cast(bf16x8, fr), vf[kt], acc);
    }
#pragma unroll
    for (int r = 0; r < 16; ++r) {
      int query = 32 * ni + (r & 3) + 8 * (r >> 2) + 4 * h5;
      if (ni == 0 || query < 49)
        out[(tokbase + query) * 384 + h * 32 + l31] = f2b(acc[r]);
    }
  }
}

// ---------------------------------------------------------------- launch
extern "C" void kernel_launch(void* const* d_in, const int* in_sizes, int n_in,
                              void* d_out, int out_size, void* d_ws,
                              size_t ws_size, hipStream_t stream) {
  const float* x = (const float*)d_in[0];
  const float* n1g = (const float*)d_in[1];
  const float* n1b = (const float*)d_in[2];
  const float* qkvw = (const float*)d_in[3];
  const float* qkvb = (const float*)d_in[4];
  const float* projw = (const float*)d_in[5];
  const float* projb = (const float*)d_in[6];
  const float* rpb = (const float*)d_in[7];
  const float* n2g = (const float*)d_in[8];
  const float* n2b = (const float*)d_in[9];
  const float* fc1w = (const float*)d_in[10];
  const float* fc1b = (const float*)d_in[11];
  const float* fc2w = (const float*)d_in[12];
  const float* fc2b = (const float*)d_in[13];
  float* out = (float*)d_out;

  char* ws = (char*)d_ws;
  short* w_qkvT = (short*)(ws + 0);            // 884736 B
  short* w_projT = (short*)(ws + 884736);      // 294912 B
  short* w_fc1T = (short*)(ws + 1179648);      // 1179648 B
  short* w_fc2T = (short*)(ws + 2359296);      // 1179648 B
  float* w_qb = (float*)(ws + 3538944);        // 4608 B
  float* tbl = (float*)(ws + 3543552);         // 786432 B
  const size_t o_qkv = 4329984;
  short* qkvbuf = (short*)(ws + o_qkv);        // 462422016 B
  const size_t o_hwin = o_qkv + 462422016ull;
  short* hwin = (short*)(ws + o_hwin);         // 154140672 B
  const size_t o_fc1 = o_hwin + 154140672ull;

  int NC;
  size_t fc1_off = o_fc1;
  if (ws_size >= o_fc1 + 616562688ull) NC = 1;
  else if (ws_size >= o_fc1 + 308281344ull) NC = 2;
  else if (ws_size >= o_fc1 + 154140672ull) NC = 4;
  else { NC = 4; fc1_off = o_hwin; }
  short* fc1c = (short*)(ws + fc1_off);
  short* h2 = qkvbuf;

  const float qscale = 0.17677669529663687f;

  convT_k<<<(442368 + 255) / 256, 256, 0, stream>>>(qkvw, w_qkvT, 384, 1152, 384, qscale);
  convT_k<<<(147456 + 255) / 256, 256, 0, stream>>>(projw, w_projT, 384, 384, 0, 1.f);
  convT_k<<<(589824 + 255) / 256, 256, 0, stream>>>(fc1w, w_fc1T, 384, 1536, 0, 1.f);
  convT_k<<<(589824 + 255) / 256, 256, 0, stream>>>(fc2w, w_fc2T, 1536, 384, 0, 1.f);
  scale_bias_k<<<5, 256, 0, stream>>>(qkvb, w_qb, 1152, 384, qscale);
  biasmask_k<<<768, 256, 0, stream>>>(rpb, tbl);

  ln1_k<<<50176, 256, 0, stream>>>(x, n1g, n1b, hwin);
  gemm_qkv_k<<<dim3(9, 1568), 256, 0, stream>>>(hwin, 384, w_qkvT, 384, w_qb,
                                                384, qkvbuf, 1152, nullptr,
                                                nullptr);
  attn_k<<<12288, 256, 0, stream>>>(qkvbuf, tbl, hwin);
  gemm_proj_k<<<dim3(3, 1568), 256, 0, stream>>>(hwin, 384, w_projT, 384,
                                                 projb, 384, nullptr, 384, out,
                                                 x);
  ln2_k<<<50176, 256, 0, stream>>>(out, n2g, n2b, h2);
  const int CK = 1536 / NC;
  for (int c = 0; c < NC; ++c) {
    gemm_fc1_k<<<dim3(CK >> 7, 1568), 256, 0, stream>>>(
        h2, 384, w_fc1T + (size_t)c * CK * 384, 384, fc1b + c * CK, 384, fc1c,
        CK, nullptr, nullptr);
    gemm_fc2_k<<<dim3(3, 1568), 256, 0, stream>>>(
        fc1c, CK, w_fc2T + c * CK, 1536, (c == 0) ? fc2b : nullptr, CK,
        nullptr, 384, out, nullptr);
  }
}